// Round 7
// baseline (977.309 us; speedup 1.0000x reference)
//
#include <hip/hip_runtime.h>

#define NSTEPS 4
#define SN (8192 * 64)

typedef unsigned short u16;
typedef unsigned int   u32;
typedef unsigned long long u64;
typedef __bf16 bf16x8 __attribute__((ext_vector_type(8)));
typedef float  f32x4  __attribute__((ext_vector_type(4)));

typedef __attribute__((address_space(1))) void gvoid_t;
typedef __attribute__((address_space(3))) void lvoid_t;

__device__ __forceinline__ void async_copy16(const void* g, void* l) {
  __builtin_amdgcn_global_load_lds((gvoid_t*)g, (lvoid_t*)l, 16, 0, 0);
}
__device__ __forceinline__ u16 bfc(float x) {
  union { __bf16 b; u16 u; } v; v.b = (__bf16)x; return v.u;
}
__device__ __forceinline__ u64 pack4(float a, float b, float c, float d) {
  return (u64)bfc(a) | ((u64)bfc(b) << 16) | ((u64)bfc(c) << 32) | ((u64)bfc(d) << 48);
}
__device__ __forceinline__ float ftanh(float x) {
  float e = __expf(2.f * x);
  return 1.f - 2.f / (e + 1.f);
}

// ---------------- prep kernels ----------------

// out[C][R] = bf16(in[R][C])
__global__ __launch_bounds__(256) void k_transpose_cast(
    const float* __restrict__ in, u16* __restrict__ out, int R, int C) {
  __shared__ float t[64][65];
  int tr = blockIdx.x * 64, tc = blockIdx.y * 64;
  int lr = threadIdx.x >> 6, lc = threadIdx.x & 63;
#pragma unroll
  for (int i = 0; i < 16; ++i) {
    int r = i * 4 + lr;
    t[r][lc] = in[(size_t)(tr + r) * C + tc + lc];
  }
  __syncthreads();
#pragma unroll
  for (int i = 0; i < 16; ++i) {
    int c = i * 4 + lr;
    out[(size_t)(tc + c) * R + tr + lc] = bfc(t[lc][c]);
  }
}

// base1[j] = b1[j] + sum_c ctx[c] * W1[(65+c)*1024 + j]
__global__ __launch_bounds__(256) void k_base1(
    const float* __restrict__ W1, const float* __restrict__ b1,
    const float* __restrict__ ctx, float* __restrict__ base1) {
  int j = blockIdx.x * 256 + threadIdx.x;
  float s = b1[j];
  for (int c = 0; c < 256; ++c)
    s += ctx[c] * W1[(size_t)(65 + c) * 1024 + j];
  base1[j] = s;
}

// Pack W[K][N] f32 -> fragment-linear bf16: fid = nt*KS + ks, lane holds
// W[ks*32+(lane>>4)*8+j][nt*16+(lane&15)], j=0..7
__global__ __launch_bounds__(256) void k_pack(
    const float* __restrict__ W, u16* __restrict__ P, int ksl, int N) {
  int gid = blockIdx.x * 256 + threadIdx.x;
  int lane = gid & 63, fid = gid >> 6;
  int ks = fid & ((1 << ksl) - 1);
  int nt = fid >> ksl;
  int n  = nt * 16 + (lane & 15);
  int k0 = ks * 32 + (lane >> 4) * 8;
  u64 lo = pack4(W[(size_t)k0 * N + n], W[(size_t)(k0 + 1) * N + n],
                 W[(size_t)(k0 + 2) * N + n], W[(size_t)(k0 + 3) * N + n]);
  u64 hi = pack4(W[(size_t)(k0 + 4) * N + n], W[(size_t)(k0 + 5) * N + n],
                 W[(size_t)(k0 + 6) * N + n], W[(size_t)(k0 + 7) * N + n]);
  u64* dst = (u64*)(P + (size_t)gid * 8);
  dst[0] = lo; dst[1] = hi;
}

// ---------------- k_l1: RK-update + layer1 (h1 computed ONCE) ----------------
// grid 256 x 32 rows. mode 0: x=theta0. mode 1 (s>0): kv=sum(kpart)+b3,
// acb+=wgp*kv, x=th+a_h*kv. mode 2 (s==0,step>0): th+=acb+wgp*kv, acb=0, x=th.
// GEMM with swapped operands: D[n][sample] -> lane holds 4 consecutive n cols
// for one sample; pack u64 -> per-wave LDS bounce -> coalesced h1 store.
__global__ __launch_bounds__(512, 4) void k_l1(
    const float* __restrict__ theta0, float* __restrict__ th,
    float* __restrict__ acb, const float* __restrict__ kpart,
    const float* __restrict__ b3, const float* __restrict__ base1,
    const float* __restrict__ w1t, const u16* __restrict__ P1,
    u16* __restrict__ h1, float t_s, float a_h, float wgp, int mode) {
  __shared__ u16 xs[32 * 64];          // 4 KB, 128B rows, slot ^= row&7
  __shared__ float bias[1024];         // 4 KB
  __shared__ u16 bounce[8][32 * 16];   // 8 KB, 1 KB per wave
  const int tid = threadIdx.x, wid = tid >> 6, lane = tid & 63;
  const int lrow = lane & 15, lk4 = lane >> 4;
  const int brow = blockIdx.x * 32;

  bias[tid]       = base1[tid]       + t_s * w1t[tid];
  bias[tid + 512] = base1[tid + 512] + t_s * w1t[tid + 512];

  // prologue: 2048 state elems, 4 per thread
  {
    int row = tid >> 4, d = (tid & 15) * 4;
    int gi = (brow + row) * 64 + d;
    f32x4 x;
    if (mode == 0) {
      x = *(const f32x4*)(theta0 + gi);
    } else {
      f32x4 kv = *(const f32x4*)(kpart + gi);
      f32x4 k1 = *(const f32x4*)(kpart + SN + gi);
      f32x4 k2 = *(const f32x4*)(kpart + 2 * SN + gi);
      f32x4 k3 = *(const f32x4*)(kpart + 3 * SN + gi);
      f32x4 bv = *(const f32x4*)(b3 + d);
      f32x4 t  = *(f32x4*)(th + gi);
      f32x4 a  = *(f32x4*)(acb + gi);
#pragma unroll
      for (int j = 0; j < 4; ++j) kv[j] += k1[j] + k2[j] + k3[j] + bv[j];
      if (mode == 1) {
#pragma unroll
        for (int j = 0; j < 4; ++j) { a[j] += wgp * kv[j]; x[j] = t[j] + a_h * kv[j]; }
        *(f32x4*)(acb + gi) = a;
      } else {
#pragma unroll
        for (int j = 0; j < 4; ++j) t[j] += a[j] + wgp * kv[j];
        *(f32x4*)(th + gi) = t;
        f32x4 z = {0.f, 0.f, 0.f, 0.f};
        *(f32x4*)(acb + gi) = z;
        x = t;
      }
    }
    int slot = d >> 3, half = (d >> 2) & 1;
    *(u64*)((char*)xs + row * 128 + ((slot ^ (row & 7)) << 4) + half * 8)
        = pack4(x[0], x[1], x[2], x[3]);
  }
  __syncthreads();

  u16* bnc = &bounce[wid][0];
#pragma unroll 1
  for (int nt = 0; nt < 8; ++nt) {
    const int n0 = wid * 128 + nt * 16;
    f32x4 acc[2] = {{0.f,0.f,0.f,0.f},{0.f,0.f,0.f,0.f}};
#pragma unroll
    for (int ks = 0; ks < 2; ++ks) {
      bf16x8 pw = *(const bf16x8*)(P1 + ((size_t)((n0 >> 4) * 2 + ks) << 9) + lane * 8);
#pragma unroll
      for (int st = 0; st < 2; ++st) {
        int row = st * 16 + lrow;
        bf16x8 xa = *(const bf16x8*)((char*)xs + row * 128 +
                                     (((ks * 4 + lk4) ^ (row & 7)) << 4));
        acc[st] = __builtin_amdgcn_mfma_f32_16x16x32_bf16(pw, xa, acc[st], 0, 0, 0);
      }
    }
    float bb0 = bias[n0 + lk4 * 4], bb1 = bias[n0 + lk4 * 4 + 1];
    float bb2 = bias[n0 + lk4 * 4 + 2], bb3 = bias[n0 + lk4 * 4 + 3];
#pragma unroll
    for (int st = 0; st < 2; ++st) {
      u64 pk = pack4(ftanh(acc[st][0] + bb0), ftanh(acc[st][1] + bb1),
                     ftanh(acc[st][2] + bb2), ftanh(acc[st][3] + bb3));
      *(u64*)((char*)bnc + (st * 16 + lrow) * 32 + lk4 * 8) = pk;
    }
    asm volatile("s_waitcnt lgkmcnt(0)" ::: "memory");
    bf16x8 ld = *(const bf16x8*)((char*)bnc + lane * 16);
    *(bf16x8*)(h1 + (size_t)(brow + (lane >> 1)) * 1024 + n0 + (lane & 1) * 8) = ld;
  }
}

// ---------------- k_fwd: layer2 + tanh + layer3-partial ----------------
// Block 64 samples x 256 h2 cols (grid 128 x 4), 512 thr, BK=64, dbuf.
// Swapped MFMA -> D[h2col][sample]; h2 tile tanh'd into LDS (overlay Bb);
// L3 partial vs packed W3 -> kpart[y] (f32x4 stores).
__global__ __launch_bounds__(512, 4) void k_fwd(
    const u16* __restrict__ h1, const u16* __restrict__ W2T,
    const float* __restrict__ b2, const u16* __restrict__ P3,
    float* __restrict__ kpart) {
  __shared__ u16 Ab[2][64 * 64];     // 2 x 8 KB
  __shared__ u16 Bb[2][256 * 64];    // 2 x 32 KB ; overlay: h2L[64][256]
  __shared__ float b2l[256];         // 1 KB
  const int tid = threadIdx.x, wid = tid >> 6, lane = tid & 63;
  const int lrow = lane & 15, lk4 = lane >> 4;
  const int brow = blockIdx.x * 64, bcol = blockIdx.y * 256;
  const int wm = wid >> 2, wn = wid & 3;    // samples 2x32, h2cols 4x64

  if (tid < 256) b2l[tid] = b2[bcol + tid];

  auto stageA = [&](int buf, int k0) {
    int row = tid >> 3, sl = tid & 7;
    async_copy16((const char*)h1 + ((size_t)(brow + row) * 1024 + k0 +
                                    ((sl ^ (row & 7)) * 8)) * 2,
                 (char*)&Ab[buf][0] + tid * 16);
  };
  auto stageB = [&](int buf, int k0) {
#pragma unroll
    for (int i = 0; i < 4; ++i) {
      int sid = i * 512 + tid;
      int row = sid >> 3, sl = sid & 7;
      async_copy16((const char*)W2T + ((size_t)(bcol + row) * 1024 + k0 +
                                       ((sl ^ (row & 7)) * 8)) * 2,
                   (char*)&Bb[buf][0] + i * 8192 + tid * 16);
    }
  };

  stageA(0, 0); stageB(0, 0);
  __syncthreads();

  f32x4 acc[4][2] = {};
  int cur = 0;
  for (int t = 0; t < 16; ++t) {
    if (t < 15) { stageA(cur ^ 1, (t + 1) * 64); stageB(cur ^ 1, (t + 1) * 64); }
    bf16x8 bf[4][2], af[2][2];
#pragma unroll
    for (int n = 0; n < 4; ++n)
#pragma unroll
      for (int kk = 0; kk < 2; ++kk) {
        int row = wn * 64 + n * 16 + lrow;
        bf[n][kk] = *(const bf16x8*)((const char*)&Bb[cur][0] + row * 128 +
                                     (((kk * 4 + lk4) ^ (row & 7)) << 4));
      }
#pragma unroll
    for (int m = 0; m < 2; ++m)
#pragma unroll
      for (int kk = 0; kk < 2; ++kk) {
        int row = wm * 32 + m * 16 + lrow;
        af[m][kk] = *(const bf16x8*)((const char*)&Ab[cur][0] + row * 128 +
                                     (((kk * 4 + lk4) ^ (row & 7)) << 4));
      }
#pragma unroll
    for (int kk = 0; kk < 2; ++kk)
#pragma unroll
      for (int n = 0; n < 4; ++n)
#pragma unroll
        for (int m = 0; m < 2; ++m)
          acc[n][m] = __builtin_amdgcn_mfma_f32_16x16x32_bf16(bf[n][kk], af[m][kk],
                                                              acc[n][m], 0, 0, 0);
    __syncthreads();
    cur ^= 1;
  }

  // h2 tile: tanh -> h2L[64][256] (overlay Bb), swizzled 16B slots
  u16* h2L = (u16*)&Bb[0][0];
#pragma unroll
  for (int n = 0; n < 4; ++n) {
    int cb = wn * 64 + n * 16 + lk4 * 4;     // col base (4 consecutive)
    float c0 = b2l[cb], c1 = b2l[cb + 1], c2 = b2l[cb + 2], c3 = b2l[cb + 3];
    int o = cb >> 3, half = (cb >> 2) & 1;   // 16B slot / 8B half
#pragma unroll
    for (int m = 0; m < 2; ++m) {
      int smp = wm * 32 + m * 16 + lrow;
      u64 pk = pack4(ftanh(acc[n][m][0] + c0), ftanh(acc[n][m][1] + c1),
                     ftanh(acc[n][m][2] + c2), ftanh(acc[n][m][3] + c3));
      *(u64*)((char*)h2L + smp * 512 + ((o ^ (smp & 7)) << 4) + half * 8) = pk;
    }
  }
  __syncthreads();

  // L3 partial: D[kcol][sample] = W3[bcol..+256,:]^T-frag x h2L
  {
    const int ws3 = wid >> 1, wc3 = wid & 1;  // samples 4x16, kcols 2x32
    const int smp = ws3 * 16 + lrow;
    const char* Ar = (const char*)h2L + smp * 512;
    const int sx = smp & 7;
    f32x4 a3[2] = {{0.f,0.f,0.f,0.f},{0.f,0.f,0.f,0.f}};
#pragma unroll
    for (int ks = 0; ks < 8; ++ks) {
      bf16x8 hf = *(const bf16x8*)(Ar + (((ks * 4 + lk4) ^ sx) << 4));
#pragma unroll
      for (int n = 0; n < 2; ++n) {
        int fid = (wc3 * 2 + n) * 32 + blockIdx.y * 8 + ks;
        bf16x8 pw = *(const bf16x8*)(P3 + ((size_t)fid << 9) + lane * 8);
        a3[n] = __builtin_amdgcn_mfma_f32_16x16x32_bf16(pw, hf, a3[n], 0, 0, 0);
      }
    }
    float* kp = kpart + (size_t)blockIdx.y * SN;
#pragma unroll
    for (int n = 0; n < 2; ++n)
      *(f32x4*)(kp + (size_t)(brow + smp) * 64 + (wc3 * 2 + n) * 16 + lk4 * 4) = a3[n];
  }
}

// ---------------- final output ----------------
__global__ __launch_bounds__(256) void k_out(
    const float* __restrict__ th, const float* __restrict__ acb,
    const float* __restrict__ kpart, const float* __restrict__ b3,
    float* __restrict__ out, float w) {
  int gi = (blockIdx.x * 256 + threadIdx.x) * 4;
  f32x4 kv = *(const f32x4*)(kpart + gi);
  f32x4 k1 = *(const f32x4*)(kpart + SN + gi);
  f32x4 k2 = *(const f32x4*)(kpart + 2 * SN + gi);
  f32x4 k3 = *(const f32x4*)(kpart + 3 * SN + gi);
  f32x4 bv = *(const f32x4*)(b3 + (gi & 63));
  f32x4 t  = *(const f32x4*)(th + gi);
  f32x4 a  = *(const f32x4*)(acb + gi);
#pragma unroll
  for (int j = 0; j < 4; ++j)
    t[j] += a[j] + w * (kv[j] + k1[j] + k2[j] + k3[j] + bv[j]);
  *(f32x4*)(out + gi) = t;
}

// ---------------- host ----------------

extern "C" void kernel_launch(void* const* d_in, const int* in_sizes, int n_in,
                              void* d_out, int out_size, void* d_ws, size_t ws_size,
                              hipStream_t stream) {
  const float* theta0 = (const float*)d_in[0];
  const float* ctx    = (const float*)d_in[1];
  const float* W1     = (const float*)d_in[2];
  const float* b1     = (const float*)d_in[3];
  const float* W2     = (const float*)d_in[4];
  const float* b2     = (const float*)d_in[5];
  const float* W3     = (const float*)d_in[6];
  const float* b3     = (const float*)d_in[7];
  const float* w1t    = W1 + (size_t)64 * 1024;   // time row of W1

  char* ws = (char*)d_ws;
  size_t o = 0;
  float* th    = (float*)(ws + o); o += (size_t)SN * 4;            // 2 MB
  float* acb   = (float*)(ws + o); o += (size_t)SN * 4;            // 2 MB
  float* base1 = (float*)(ws + o); o += 4096;
  u16* W2T = (u16*)(ws + o); o += (size_t)1024 * 1024 * 2;         // 2 MB
  u16* P1  = (u16*)(ws + o); o += (size_t)64 * 1024 * 2;           // 128 KB
  u16* P3  = (u16*)(ws + o); o += (size_t)1024 * 64 * 2;           // 128 KB
  float* kpart = (float*)(ws + o); o += (size_t)4 * SN * 4;        // 8 MB
  u16* h1  = (u16*)(ws + o); o += (size_t)8192 * 1024 * 2;         // 16 MB

  hipMemcpyAsync(th, theta0, (size_t)SN * 4, hipMemcpyDeviceToDevice, stream);
  hipMemsetAsync(acb, 0, (size_t)SN * 4, stream);

  k_base1<<<dim3(4), 256, 0, stream>>>(W1, b1, ctx, base1);
  k_transpose_cast<<<dim3(16, 16), 256, 0, stream>>>(W2, W2T, 1024, 1024);
  k_pack<<<dim3(32), 256, 0, stream>>>(W1, P1, 1, 1024);   // 64 ntiles x 2 ks
  k_pack<<<dim3(32), 256, 0, stream>>>(W3, P3, 5, 64);     // 4 ntiles x 32 ks

  const float hs = 1.f / NSTEPS;
  const float ah[4] = {0.f, 0.5f * hs, 0.5f * hs, hs};
  const float ct[4] = {0.f, 0.5f, 0.5f, 1.f};

  for (int step = 0; step < NSTEPS; ++step) {
    for (int s = 0; s < 4; ++s) {
      int mode = (step == 0 && s == 0) ? 0 : (s == 0 ? 2 : 1);
      float wgp = (s == 0 || s == 1) ? hs / 6.f : hs / 3.f;
      float t_s = ((float)step + ct[s]) * hs;
      k_l1<<<dim3(256), 512, 0, stream>>>(theta0, th, acb, kpart, b3, base1,
                                          w1t, P1, h1, t_s, ah[s], wgp, mode);
      k_fwd<<<dim3(128, 4), 512, 0, stream>>>(h1, W2T, b2, P3, kpart);
    }
  }
  k_out<<<dim3(512), 256, 0, stream>>>(th, acb, kpart, b3, (float*)d_out, hs / 6.f);
}

// Round 8
// 843.159 us; speedup vs baseline: 1.1591x; 1.1591x over previous
//
#include <hip/hip_runtime.h>

#define NSTEPS 4
#define SN (8192 * 64)

typedef unsigned short u16;
typedef unsigned int   u32;
typedef unsigned long long u64;
typedef __bf16 bf16x8 __attribute__((ext_vector_type(8)));
typedef float  f32x4  __attribute__((ext_vector_type(4)));

typedef __attribute__((address_space(1))) void gvoid_t;
typedef __attribute__((address_space(3))) void lvoid_t;

__device__ __forceinline__ void async_copy16(const void* g, void* l) {
  __builtin_amdgcn_global_load_lds((gvoid_t*)g, (lvoid_t*)l, 16, 0, 0);
}
__device__ __forceinline__ u16 bfc(float x) {
  union { __bf16 b; u16 u; } v; v.b = (__bf16)x; return v.u;
}
__device__ __forceinline__ u64 pack4(float a, float b, float c, float d) {
  return (u64)bfc(a) | ((u64)bfc(b) << 16) | ((u64)bfc(c) << 32) | ((u64)bfc(d) << 48);
}
__device__ __forceinline__ float ftanh(float x) {
  float e = __expf(2.f * x);
  return 1.f - 2.f / (e + 1.f);
}

// ---------------- prep kernels ----------------

// out[C][R] = bf16(in[R][C])
__global__ __launch_bounds__(256) void k_transpose_cast(
    const float* __restrict__ in, u16* __restrict__ out, int R, int C) {
  __shared__ float t[64][65];
  int tr = blockIdx.x * 64, tc = blockIdx.y * 64;
  int lr = threadIdx.x >> 6, lc = threadIdx.x & 63;
#pragma unroll
  for (int i = 0; i < 16; ++i) {
    int r = i * 4 + lr;
    t[r][lc] = in[(size_t)(tr + r) * C + tc + lc];
  }
  __syncthreads();
#pragma unroll
  for (int i = 0; i < 16; ++i) {
    int c = i * 4 + lr;
    out[(size_t)(tc + c) * R + tr + lc] = bfc(t[lc][c]);
  }
}

// base1[j] = b1[j] + sum_c ctx[c] * W1[(65+c)*1024 + j]
__global__ __launch_bounds__(256) void k_base1(
    const float* __restrict__ W1, const float* __restrict__ b1,
    const float* __restrict__ ctx, float* __restrict__ base1) {
  int j = blockIdx.x * 256 + threadIdx.x;
  float s = b1[j];
  for (int c = 0; c < 256; ++c)
    s += ctx[c] * W1[(size_t)(65 + c) * 1024 + j];
  base1[j] = s;
}

// Pack W[K][N] f32 -> fragment-linear bf16: fid = nt*KS + ks, lane holds
// W[ks*32+(lane>>4)*8+j][nt*16+(lane&15)], j=0..7
__global__ __launch_bounds__(256) void k_pack(
    const float* __restrict__ W, u16* __restrict__ P, int ksl, int N) {
  int gid = blockIdx.x * 256 + threadIdx.x;
  int lane = gid & 63, fid = gid >> 6;
  int ks = fid & ((1 << ksl) - 1);
  int nt = fid >> ksl;
  int n  = nt * 16 + (lane & 15);
  int k0 = ks * 32 + (lane >> 4) * 8;
  u64 lo = pack4(W[(size_t)k0 * N + n], W[(size_t)(k0 + 1) * N + n],
                 W[(size_t)(k0 + 2) * N + n], W[(size_t)(k0 + 3) * N + n]);
  u64 hi = pack4(W[(size_t)(k0 + 4) * N + n], W[(size_t)(k0 + 5) * N + n],
                 W[(size_t)(k0 + 6) * N + n], W[(size_t)(k0 + 7) * N + n]);
  u64* dst = (u64*)(P + (size_t)gid * 8);
  dst[0] = lo; dst[1] = hi;
}

// ---------------- k_l1: RK-update + layer1 (h1 computed ONCE) ----------------
__global__ __launch_bounds__(512, 4) void k_l1(
    const float* __restrict__ theta0, float* __restrict__ th,
    float* __restrict__ acb, const float* __restrict__ kpart,
    const float* __restrict__ b3, const float* __restrict__ base1,
    const float* __restrict__ w1t, const u16* __restrict__ P1,
    u16* __restrict__ h1, float t_s, float a_h, float wgp, int mode) {
  __shared__ u16 xs[32 * 64];          // 4 KB, 128B rows, slot ^= row&7
  __shared__ float bias[1024];         // 4 KB
  __shared__ u16 bounce[8][32 * 16];   // 8 KB, 1 KB per wave
  const int tid = threadIdx.x, wid = tid >> 6, lane = tid & 63;
  const int lrow = lane & 15, lk4 = lane >> 4;
  const int brow = blockIdx.x * 32;

  bias[tid]       = base1[tid]       + t_s * w1t[tid];
  bias[tid + 512] = base1[tid + 512] + t_s * w1t[tid + 512];

  {
    int row = tid >> 4, d = (tid & 15) * 4;
    int gi = (brow + row) * 64 + d;
    f32x4 x;
    if (mode == 0) {
      x = *(const f32x4*)(theta0 + gi);
    } else {
      f32x4 kv = *(const f32x4*)(kpart + gi);
      f32x4 k1 = *(const f32x4*)(kpart + SN + gi);
      f32x4 k2 = *(const f32x4*)(kpart + 2 * SN + gi);
      f32x4 k3 = *(const f32x4*)(kpart + 3 * SN + gi);
      f32x4 bv = *(const f32x4*)(b3 + d);
      f32x4 t  = *(f32x4*)(th + gi);
      f32x4 a  = *(f32x4*)(acb + gi);
#pragma unroll
      for (int j = 0; j < 4; ++j) kv[j] += k1[j] + k2[j] + k3[j] + bv[j];
      if (mode == 1) {
#pragma unroll
        for (int j = 0; j < 4; ++j) { a[j] += wgp * kv[j]; x[j] = t[j] + a_h * kv[j]; }
        *(f32x4*)(acb + gi) = a;
      } else {
#pragma unroll
        for (int j = 0; j < 4; ++j) t[j] += a[j] + wgp * kv[j];
        *(f32x4*)(th + gi) = t;
        f32x4 z = {0.f, 0.f, 0.f, 0.f};
        *(f32x4*)(acb + gi) = z;
        x = t;
      }
    }
    int slot = d >> 3, half = (d >> 2) & 1;
    *(u64*)((char*)xs + row * 128 + ((slot ^ (row & 7)) << 4) + half * 8)
        = pack4(x[0], x[1], x[2], x[3]);
  }
  __syncthreads();

  u16* bnc = &bounce[wid][0];
#pragma unroll 1
  for (int nt = 0; nt < 8; ++nt) {
    const int n0 = wid * 128 + nt * 16;
    f32x4 acc[2] = {{0.f,0.f,0.f,0.f},{0.f,0.f,0.f,0.f}};
#pragma unroll
    for (int ks = 0; ks < 2; ++ks) {
      bf16x8 pw = *(const bf16x8*)(P1 + ((size_t)((n0 >> 4) * 2 + ks) << 9) + lane * 8);
#pragma unroll
      for (int st = 0; st < 2; ++st) {
        int row = st * 16 + lrow;
        bf16x8 xa = *(const bf16x8*)((char*)xs + row * 128 +
                                     (((ks * 4 + lk4) ^ (row & 7)) << 4));
        acc[st] = __builtin_amdgcn_mfma_f32_16x16x32_bf16(pw, xa, acc[st], 0, 0, 0);
      }
    }
    float bb0 = bias[n0 + lk4 * 4], bb1 = bias[n0 + lk4 * 4 + 1];
    float bb2 = bias[n0 + lk4 * 4 + 2], bb3 = bias[n0 + lk4 * 4 + 3];
#pragma unroll
    for (int st = 0; st < 2; ++st) {
      u64 pk = pack4(ftanh(acc[st][0] + bb0), ftanh(acc[st][1] + bb1),
                     ftanh(acc[st][2] + bb2), ftanh(acc[st][3] + bb3));
      *(u64*)((char*)bnc + (st * 16 + lrow) * 32 + lk4 * 8) = pk;
    }
    asm volatile("s_waitcnt lgkmcnt(0)" ::: "memory");
    bf16x8 ld = *(const bf16x8*)((char*)bnc + lane * 16);
    *(bf16x8*)(h1 + (size_t)(brow + (lane >> 1)) * 1024 + n0 + (lane & 1) * 8) = ld;
  }
}

// ---------------- k_fwd: layer2 + tanh + layer3-partial ----------------
// Block 64 samples x 256 h2 cols (grid 128 x 4), 256 thr = 4 waves.
// Wave tile 64 cols x 64 samples (acc[4][4]): 8 ds_read_b128 feed 16 MFMA.
// BK=32, dbuf, pair-packed 128-B LDS lines (round-6-validated swizzle).
// Swapped MFMA -> D[h2col][sample]; tanh(h2) -> LDS overlay; fused L3.
__global__ __launch_bounds__(256, 3) void k_fwd(
    const u16* __restrict__ h1, const u16* __restrict__ W2T,
    const float* __restrict__ b2, const u16* __restrict__ P3,
    float* __restrict__ kpart) {
  __shared__ u16 Ab[2][64 * 32];     // 2 x 4 KB
  __shared__ u16 Bb[2][256 * 32];    // 2 x 16 KB ; overlay: h2L[64][256] (32 KB)
  __shared__ float b2l[256];         // 1 KB
  const int tid = threadIdx.x, wid = tid >> 6, lane = tid & 63;
  const int lrow = lane & 15, lk4 = lane >> 4;
  const int brow = blockIdx.x * 64, bcol = blockIdx.y * 256;
  const int wn = wid;                 // wave col-block (4 x 64 cols)

  b2l[tid] = b2[bcol + tid];

  // pair-packed dest: slot sid -> line pr=sid>>3, s8=sid&7; logical
  // (row,kq): s8u = s8 ^ (pr&7), row = pr*2+(s8u>>2), kq = s8u&3.
  auto stageA = [&](int buf, int k0) {
    int pr = tid >> 3, s8u = (tid & 7) ^ (pr & 7);
    int row = pr * 2 + (s8u >> 2), kq = s8u & 3;
    async_copy16((const char*)h1 + ((size_t)(brow + row) * 1024 + k0 + kq * 8) * 2,
                 (char*)&Ab[buf][0] + tid * 16);
  };
  auto stageB = [&](int buf, int k0) {
#pragma unroll
    for (int i = 0; i < 4; ++i) {
      int sid = i * 256 + tid;
      int pr = sid >> 3, s8u = (sid & 7) ^ (pr & 7);
      int row = pr * 2 + (s8u >> 2), kq = s8u & 3;
      async_copy16((const char*)W2T + ((size_t)(bcol + row) * 1024 + k0 + kq * 8) * 2,
                   (char*)&Bb[buf][0] + i * 4096 + tid * 16);
    }
  };

  stageA(0, 0); stageB(0, 0);
  __syncthreads();

  f32x4 acc[4][4] = {};
  int cur = 0;
  for (int t = 0; t < 32; ++t) {
    if (t < 31) { stageA(cur ^ 1, (t + 1) * 32); stageB(cur ^ 1, (t + 1) * 32); }
    bf16x8 bf[4], af[4];
#pragma unroll
    for (int n = 0; n < 4; ++n) {
      int bn = wn * 64 + n * 16 + lrow;
      int pr = bn >> 1;
      bf[n] = *(const bf16x8*)((const char*)&Bb[cur][0] + pr * 128 +
                               ((((bn & 1) * 4 + lk4) ^ (pr & 7)) << 4));
    }
#pragma unroll
    for (int m = 0; m < 4; ++m) {
      int ar = m * 16 + lrow;
      int pr = ar >> 1;
      af[m] = *(const bf16x8*)((const char*)&Ab[cur][0] + pr * 128 +
                               ((((ar & 1) * 4 + lk4) ^ (pr & 7)) << 4));
    }
#pragma unroll
    for (int n = 0; n < 4; ++n)
#pragma unroll
      for (int m = 0; m < 4; ++m)
        acc[n][m] = __builtin_amdgcn_mfma_f32_16x16x32_bf16(bf[n], af[m],
                                                            acc[n][m], 0, 0, 0);
    __syncthreads();
    cur ^= 1;
  }

  // h2 tile: tanh -> h2L[64][256] (overlay Bb, 512B rows), swizzled slots
  u16* h2L = (u16*)&Bb[0][0];
#pragma unroll
  for (int n = 0; n < 4; ++n) {
    int cb = wn * 64 + n * 16 + lk4 * 4;     // 4 consecutive cols
    float c0 = b2l[cb], c1 = b2l[cb + 1], c2 = b2l[cb + 2], c3 = b2l[cb + 3];
    int o = cb >> 3, half = (cb >> 2) & 1;
#pragma unroll
    for (int m = 0; m < 4; ++m) {
      int smp = m * 16 + lrow;
      u64 pk = pack4(ftanh(acc[n][m][0] + c0), ftanh(acc[n][m][1] + c1),
                     ftanh(acc[n][m][2] + c2), ftanh(acc[n][m][3] + c3));
      int sl = (o & 24) | ((o & 7) ^ (smp & 7));
      *(u64*)((char*)h2L + smp * 512 + (sl << 4) + half * 8) = pk;
    }
  }
  __syncthreads();

  // L3 partial: D[kcol][sample], each wave 16 samples x 64 kcols, K=256
  {
    const int smp = wid * 16 + lrow;
    const char* Ar = (const char*)h2L + smp * 512;
    const int sx = smp & 7;
    f32x4 a3[4] = {};
#pragma unroll
    for (int ks = 0; ks < 8; ++ks) {
      int slu = ks * 4 + lk4;
      bf16x8 hf = *(const bf16x8*)(Ar + (((slu & 24) | ((slu & 7) ^ sx)) << 4));
#pragma unroll
      for (int n = 0; n < 4; ++n) {
        int fid = n * 32 + blockIdx.y * 8 + ks;
        bf16x8 pw = *(const bf16x8*)(P3 + ((size_t)fid << 9) + lane * 8);
        a3[n] = __builtin_amdgcn_mfma_f32_16x16x32_bf16(pw, hf, a3[n], 0, 0, 0);
      }
    }
    float* kp = kpart + (size_t)blockIdx.y * SN;
#pragma unroll
    for (int n = 0; n < 4; ++n)
      *(f32x4*)(kp + (size_t)(brow + smp) * 64 + n * 16 + lk4 * 4) = a3[n];
  }
}

// ---------------- final output ----------------
__global__ __launch_bounds__(256) void k_out(
    const float* __restrict__ th, const float* __restrict__ acb,
    const float* __restrict__ kpart, const float* __restrict__ b3,
    float* __restrict__ out, float w) {
  int gi = (blockIdx.x * 256 + threadIdx.x) * 4;
  f32x4 kv = *(const f32x4*)(kpart + gi);
  f32x4 k1 = *(const f32x4*)(kpart + SN + gi);
  f32x4 k2 = *(const f32x4*)(kpart + 2 * SN + gi);
  f32x4 k3 = *(const f32x4*)(kpart + 3 * SN + gi);
  f32x4 bv = *(const f32x4*)(b3 + (gi & 63));
  f32x4 t  = *(const f32x4*)(th + gi);
  f32x4 a  = *(const f32x4*)(acb + gi);
#pragma unroll
  for (int j = 0; j < 4; ++j)
    t[j] += a[j] + w * (kv[j] + k1[j] + k2[j] + k3[j] + bv[j]);
  *(f32x4*)(out + gi) = t;
}

// ---------------- host ----------------

extern "C" void kernel_launch(void* const* d_in, const int* in_sizes, int n_in,
                              void* d_out, int out_size, void* d_ws, size_t ws_size,
                              hipStream_t stream) {
  const float* theta0 = (const float*)d_in[0];
  const float* ctx    = (const float*)d_in[1];
  const float* W1     = (const float*)d_in[2];
  const float* b1     = (const float*)d_in[3];
  const float* W2     = (const float*)d_in[4];
  const float* b2     = (const float*)d_in[5];
  const float* W3     = (const float*)d_in[6];
  const float* b3     = (const float*)d_in[7];
  const float* w1t    = W1 + (size_t)64 * 1024;   // time row of W1

  char* ws = (char*)d_ws;
  size_t o = 0;
  float* th    = (float*)(ws + o); o += (size_t)SN * 4;            // 2 MB
  float* acb   = (float*)(ws + o); o += (size_t)SN * 4;            // 2 MB
  float* base1 = (float*)(ws + o); o += 4096;
  u16* W2T = (u16*)(ws + o); o += (size_t)1024 * 1024 * 2;         // 2 MB
  u16* P1  = (u16*)(ws + o); o += (size_t)64 * 1024 * 2;           // 128 KB
  u16* P3  = (u16*)(ws + o); o += (size_t)1024 * 64 * 2;           // 128 KB
  float* kpart = (float*)(ws + o); o += (size_t)4 * SN * 4;        // 8 MB
  u16* h1  = (u16*)(ws + o); o += (size_t)8192 * 1024 * 2;         // 16 MB

  hipMemcpyAsync(th, theta0, (size_t)SN * 4, hipMemcpyDeviceToDevice, stream);
  hipMemsetAsync(acb, 0, (size_t)SN * 4, stream);

  k_base1<<<dim3(4), 256, 0, stream>>>(W1, b1, ctx, base1);
  k_transpose_cast<<<dim3(16, 16), 256, 0, stream>>>(W2, W2T, 1024, 1024);
  k_pack<<<dim3(32), 256, 0, stream>>>(W1, P1, 1, 1024);   // 64 ntiles x 2 ks
  k_pack<<<dim3(32), 256, 0, stream>>>(W3, P3, 5, 64);     // 4 ntiles x 32 ks

  const float hs = 1.f / NSTEPS;
  const float ah[4] = {0.f, 0.5f * hs, 0.5f * hs, hs};
  const float ct[4] = {0.f, 0.5f, 0.5f, 1.f};

  for (int step = 0; step < NSTEPS; ++step) {
    for (int s = 0; s < 4; ++s) {
      int mode = (step == 0 && s == 0) ? 0 : (s == 0 ? 2 : 1);
      float wgp = (s == 0 || s == 1) ? hs / 6.f : hs / 3.f;
      float t_s = ((float)step + ct[s]) * hs;
      k_l1<<<dim3(256), 512, 0, stream>>>(theta0, th, acb, kpart, b3, base1,
                                          w1t, P1, h1, t_s, ah[s], wgp, mode);
      k_fwd<<<dim3(128, 4), 256, 0, stream>>>(h1, W2T, b2, P3, kpart);
    }
  }
  k_out<<<dim3(512), 256, 0, stream>>>(th, acb, kpart, b3, (float*)d_out, hs / 6.f);
}

// Round 9
// 774.503 us; speedup vs baseline: 1.2619x; 1.0886x over previous
//
#include <hip/hip_runtime.h>

#define NSTEPS 4
#define SN (8192 * 64)

typedef unsigned short u16;
typedef unsigned int   u32;
typedef unsigned long long u64;
typedef __bf16 bf16x8 __attribute__((ext_vector_type(8)));
typedef float  f32x4  __attribute__((ext_vector_type(4)));

typedef __attribute__((address_space(1))) void gvoid_t;
typedef __attribute__((address_space(3))) void lvoid_t;

__device__ __forceinline__ void async_copy16(const void* g, void* l) {
  __builtin_amdgcn_global_load_lds((gvoid_t*)g, (lvoid_t*)l, 16, 0, 0);
}
__device__ __forceinline__ u16 bfc(float x) {
  union { __bf16 b; u16 u; } v; v.b = (__bf16)x; return v.u;
}
__device__ __forceinline__ u64 pack4(float a, float b, float c, float d) {
  return (u64)bfc(a) | ((u64)bfc(b) << 16) | ((u64)bfc(c) << 32) | ((u64)bfc(d) << 48);
}
__device__ __forceinline__ float ftanh(float x) {
  float e = __expf(2.f * x);
  return 1.f - 2.f / (e + 1.f);
}

// ---------------- prep kernels ----------------

// out[C][R] = bf16(in[R][C])
__global__ __launch_bounds__(256) void k_transpose_cast(
    const float* __restrict__ in, u16* __restrict__ out, int R, int C) {
  __shared__ float t[64][65];
  int tr = blockIdx.x * 64, tc = blockIdx.y * 64;
  int lr = threadIdx.x >> 6, lc = threadIdx.x & 63;
#pragma unroll
  for (int i = 0; i < 16; ++i) {
    int r = i * 4 + lr;
    t[r][lc] = in[(size_t)(tr + r) * C + tc + lc];
  }
  __syncthreads();
#pragma unroll
  for (int i = 0; i < 16; ++i) {
    int c = i * 4 + lr;
    out[(size_t)(tc + c) * R + tr + lc] = bfc(t[lc][c]);
  }
}

// base1[j] = b1[j] + sum_c ctx[c] * W1[(65+c)*1024 + j]
__global__ __launch_bounds__(256) void k_base1(
    const float* __restrict__ W1, const float* __restrict__ b1,
    const float* __restrict__ ctx, float* __restrict__ base1) {
  int j = blockIdx.x * 256 + threadIdx.x;
  float s = b1[j];
  for (int c = 0; c < 256; ++c)
    s += ctx[c] * W1[(size_t)(65 + c) * 1024 + j];
  base1[j] = s;
}

// Pack W[K][N] f32 -> fragment-linear bf16: fid = nt*KS + ks, lane holds
// W[ks*32+(lane>>4)*8+j][nt*16+(lane&15)], j=0..7
__global__ __launch_bounds__(256) void k_pack(
    const float* __restrict__ W, u16* __restrict__ P, int ksl, int N) {
  int gid = blockIdx.x * 256 + threadIdx.x;
  int lane = gid & 63, fid = gid >> 6;
  int ks = fid & ((1 << ksl) - 1);
  int nt = fid >> ksl;
  int n  = nt * 16 + (lane & 15);
  int k0 = ks * 32 + (lane >> 4) * 8;
  u64 lo = pack4(W[(size_t)k0 * N + n], W[(size_t)(k0 + 1) * N + n],
                 W[(size_t)(k0 + 2) * N + n], W[(size_t)(k0 + 3) * N + n]);
  u64 hi = pack4(W[(size_t)(k0 + 4) * N + n], W[(size_t)(k0 + 5) * N + n],
                 W[(size_t)(k0 + 6) * N + n], W[(size_t)(k0 + 7) * N + n]);
  u64* dst = (u64*)(P + (size_t)gid * 8);
  dst[0] = lo; dst[1] = hi;
}

// ---------------- k_l1: RK-update + layer1 (h1 computed ONCE) ----------------
__global__ __launch_bounds__(512, 4) void k_l1(
    const float* __restrict__ theta0, float* __restrict__ th,
    float* __restrict__ acb, const float* __restrict__ kpart,
    const float* __restrict__ b3, const float* __restrict__ base1,
    const float* __restrict__ w1t, const u16* __restrict__ P1,
    u16* __restrict__ h1, float t_s, float a_h, float wgp, int mode) {
  __shared__ u16 xs[32 * 64];          // 4 KB, 128B rows, slot ^= row&7
  __shared__ float bias[1024];         // 4 KB
  __shared__ u16 bounce[8][32 * 16];   // 8 KB, 1 KB per wave
  const int tid = threadIdx.x, wid = tid >> 6, lane = tid & 63;
  const int lrow = lane & 15, lk4 = lane >> 4;
  const int brow = blockIdx.x * 32;

  bias[tid]       = base1[tid]       + t_s * w1t[tid];
  bias[tid + 512] = base1[tid + 512] + t_s * w1t[tid + 512];

  {
    int row = tid >> 4, d = (tid & 15) * 4;
    int gi = (brow + row) * 64 + d;
    f32x4 x;
    if (mode == 0) {
      x = *(const f32x4*)(theta0 + gi);
    } else {
      f32x4 kv = *(const f32x4*)(kpart + gi);
      f32x4 k1 = *(const f32x4*)(kpart + SN + gi);
      f32x4 k2 = *(const f32x4*)(kpart + 2 * SN + gi);
      f32x4 k3 = *(const f32x4*)(kpart + 3 * SN + gi);
      f32x4 bv = *(const f32x4*)(b3 + d);
      f32x4 t  = *(f32x4*)(th + gi);
      f32x4 a  = *(f32x4*)(acb + gi);
#pragma unroll
      for (int j = 0; j < 4; ++j) kv[j] += k1[j] + k2[j] + k3[j] + bv[j];
      if (mode == 1) {
#pragma unroll
        for (int j = 0; j < 4; ++j) { a[j] += wgp * kv[j]; x[j] = t[j] + a_h * kv[j]; }
        *(f32x4*)(acb + gi) = a;
      } else {
#pragma unroll
        for (int j = 0; j < 4; ++j) t[j] += a[j] + wgp * kv[j];
        *(f32x4*)(th + gi) = t;
        f32x4 z = {0.f, 0.f, 0.f, 0.f};
        *(f32x4*)(acb + gi) = z;
        x = t;
      }
    }
    int slot = d >> 3, half = (d >> 2) & 1;
    *(u64*)((char*)xs + row * 128 + ((slot ^ (row & 7)) << 4) + half * 8)
        = pack4(x[0], x[1], x[2], x[3]);
  }
  __syncthreads();

  u16* bnc = &bounce[wid][0];
#pragma unroll 1
  for (int nt = 0; nt < 8; ++nt) {
    const int n0 = wid * 128 + nt * 16;
    f32x4 acc[2] = {{0.f,0.f,0.f,0.f},{0.f,0.f,0.f,0.f}};
#pragma unroll
    for (int ks = 0; ks < 2; ++ks) {
      bf16x8 pw = *(const bf16x8*)(P1 + ((size_t)((n0 >> 4) * 2 + ks) << 9) + lane * 8);
#pragma unroll
      for (int st = 0; st < 2; ++st) {
        int row = st * 16 + lrow;
        bf16x8 xa = *(const bf16x8*)((char*)xs + row * 128 +
                                     (((ks * 4 + lk4) ^ (row & 7)) << 4));
        acc[st] = __builtin_amdgcn_mfma_f32_16x16x32_bf16(pw, xa, acc[st], 0, 0, 0);
      }
    }
    float bb0 = bias[n0 + lk4 * 4], bb1 = bias[n0 + lk4 * 4 + 1];
    float bb2 = bias[n0 + lk4 * 4 + 2], bb3 = bias[n0 + lk4 * 4 + 3];
#pragma unroll
    for (int st = 0; st < 2; ++st) {
      u64 pk = pack4(ftanh(acc[st][0] + bb0), ftanh(acc[st][1] + bb1),
                     ftanh(acc[st][2] + bb2), ftanh(acc[st][3] + bb3));
      *(u64*)((char*)bnc + (st * 16 + lrow) * 32 + lk4 * 8) = pk;
    }
    asm volatile("s_waitcnt lgkmcnt(0)" ::: "memory");
    bf16x8 ld = *(const bf16x8*)((char*)bnc + lane * 16);
    *(bf16x8*)(h1 + (size_t)(brow + (lane >> 1)) * 1024 + n0 + (lane & 1) * 8) = ld;
  }
}

// ---------------- k_fwd: layer2 + tanh + layer3-partial ----------------
// Block 64 samples x 256 h2 cols (grid 128 x 4), 256 thr = 4 waves.
// Wave tile 64 cols x 64 samples (acc[4][4]); BK=32, pair-packed swizzle.
// K-loop: counted-vmcnt 2-deep pipeline (T4): 5 loads/thread/tile, raw
// s_barrier, vmcnt(5) in steady state — prefetch stays in flight across
// barriers; only the last tile drains to 0.
__global__ __launch_bounds__(256, 3) void k_fwd(
    const u16* __restrict__ h1, const u16* __restrict__ W2T,
    const float* __restrict__ b2, const u16* __restrict__ P3,
    float* __restrict__ kpart) {
  __shared__ u16 Ab[2][64 * 32];     // 2 x 4 KB
  __shared__ u16 Bb[2][256 * 32];    // 2 x 16 KB ; overlay: h2L[64][256] (32 KB)
  __shared__ float b2l[256];         // 1 KB
  const int tid = threadIdx.x, wid = tid >> 6, lane = tid & 63;
  const int lrow = lane & 15, lk4 = lane >> 4;
  const int brow = blockIdx.x * 64, bcol = blockIdx.y * 256;
  const int wn = wid;                 // wave col-block (4 x 64 cols)

  b2l[tid] = b2[bcol + tid];

  // pair-packed dest: slot sid -> line pr=sid>>3, s8=sid&7; logical
  // (row,kq): s8u = s8 ^ (pr&7), row = pr*2+(s8u>>2), kq = s8u&3.
  auto stageA = [&](int buf, int k0) {
    int pr = tid >> 3, s8u = (tid & 7) ^ (pr & 7);
    int row = pr * 2 + (s8u >> 2), kq = s8u & 3;
    async_copy16((const char*)h1 + ((size_t)(brow + row) * 1024 + k0 + kq * 8) * 2,
                 (char*)&Ab[buf][0] + tid * 16);
  };
  auto stageB = [&](int buf, int k0) {
#pragma unroll
    for (int i = 0; i < 4; ++i) {
      int sid = i * 256 + tid;
      int pr = sid >> 3, s8u = (sid & 7) ^ (pr & 7);
      int row = pr * 2 + (s8u >> 2), kq = s8u & 3;
      async_copy16((const char*)W2T + ((size_t)(bcol + row) * 1024 + k0 + kq * 8) * 2,
                   (char*)&Bb[buf][0] + i * 4096 + tid * 16);
    }
  };

  // prologue: 2 tiles in flight (10 loads/thread outstanding)
  stageA(0, 0);  stageB(0, 0);
  stageA(1, 32); stageB(1, 32);

  f32x4 acc[4][4] = {};
  int cur = 0;
#pragma unroll 1
  for (int t = 0; t < 32; ++t) {
    // tile t landed (5 newer loads for t+1 may stay in flight)
    if (t < 31) asm volatile("s_waitcnt vmcnt(5)" ::: "memory");
    else        asm volatile("s_waitcnt vmcnt(0)" ::: "memory");
    __builtin_amdgcn_s_barrier();

    bf16x8 bf[4], af[4];
#pragma unroll
    for (int n = 0; n < 4; ++n) {
      int bn = wn * 64 + n * 16 + lrow;
      int pr = bn >> 1;
      bf[n] = *(const bf16x8*)((const char*)&Bb[cur][0] + pr * 128 +
                               ((((bn & 1) * 4 + lk4) ^ (pr & 7)) << 4));
    }
#pragma unroll
    for (int m = 0; m < 4; ++m) {
      int ar = m * 16 + lrow;
      int pr = ar >> 1;
      af[m] = *(const bf16x8*)((const char*)&Ab[cur][0] + pr * 128 +
                               ((((ar & 1) * 4 + lk4) ^ (pr & 7)) << 4));
    }
    asm volatile("s_waitcnt lgkmcnt(0)" ::: "memory");
    __builtin_amdgcn_s_barrier();      // all waves done reading buf[cur]

    if (t < 30) { stageA(cur, (t + 2) * 32); stageB(cur, (t + 2) * 32); }

#pragma unroll
    for (int n = 0; n < 4; ++n)
#pragma unroll
      for (int m = 0; m < 4; ++m)
        acc[n][m] = __builtin_amdgcn_mfma_f32_16x16x32_bf16(bf[n], af[m],
                                                            acc[n][m], 0, 0, 0);
    cur ^= 1;
  }

  // h2 tile: tanh -> h2L[64][256] (overlay Bb, 512B rows), swizzled slots
  u16* h2L = (u16*)&Bb[0][0];
#pragma unroll
  for (int n = 0; n < 4; ++n) {
    int cb = wn * 64 + n * 16 + lk4 * 4;     // 4 consecutive cols
    float c0 = b2l[cb], c1 = b2l[cb + 1], c2 = b2l[cb + 2], c3 = b2l[cb + 3];
    int o = cb >> 3, half = (cb >> 2) & 1;
#pragma unroll
    for (int m = 0; m < 4; ++m) {
      int smp = m * 16 + lrow;
      u64 pk = pack4(ftanh(acc[n][m][0] + c0), ftanh(acc[n][m][1] + c1),
                     ftanh(acc[n][m][2] + c2), ftanh(acc[n][m][3] + c3));
      int sl = (o & 24) | ((o & 7) ^ (smp & 7));
      *(u64*)((char*)h2L + smp * 512 + (sl << 4) + half * 8) = pk;
    }
  }
  __syncthreads();

  // L3 partial: D[kcol][sample], each wave 16 samples x 64 kcols, K=256
  {
    const int smp = wid * 16 + lrow;
    const char* Ar = (const char*)h2L + smp * 512;
    const int sx = smp & 7;
    f32x4 a3[4] = {};
#pragma unroll
    for (int ks = 0; ks < 8; ++ks) {
      int slu = ks * 4 + lk4;
      bf16x8 hf = *(const bf16x8*)(Ar + (((slu & 24) | ((slu & 7) ^ sx)) << 4));
#pragma unroll
      for (int n = 0; n < 4; ++n) {
        int fid = n * 32 + blockIdx.y * 8 + ks;
        bf16x8 pw = *(const bf16x8*)(P3 + ((size_t)fid << 9) + lane * 8);
        a3[n] = __builtin_amdgcn_mfma_f32_16x16x32_bf16(pw, hf, a3[n], 0, 0, 0);
      }
    }
    float* kp = kpart + (size_t)blockIdx.y * SN;
#pragma unroll
    for (int n = 0; n < 4; ++n)
      *(f32x4*)(kp + (size_t)(brow + smp) * 64 + n * 16 + lk4 * 4) = a3[n];
  }
}

// ---------------- final output ----------------
__global__ __launch_bounds__(256) void k_out(
    const float* __restrict__ th, const float* __restrict__ acb,
    const float* __restrict__ kpart, const float* __restrict__ b3,
    float* __restrict__ out, float w) {
  int gi = (blockIdx.x * 256 + threadIdx.x) * 4;
  f32x4 kv = *(const f32x4*)(kpart + gi);
  f32x4 k1 = *(const f32x4*)(kpart + SN + gi);
  f32x4 k2 = *(const f32x4*)(kpart + 2 * SN + gi);
  f32x4 k3 = *(const f32x4*)(kpart + 3 * SN + gi);
  f32x4 bv = *(const f32x4*)(b3 + (gi & 63));
  f32x4 t  = *(const f32x4*)(th + gi);
  f32x4 a  = *(const f32x4*)(acb + gi);
#pragma unroll
  for (int j = 0; j < 4; ++j)
    t[j] += a[j] + w * (kv[j] + k1[j] + k2[j] + k3[j] + bv[j]);
  *(f32x4*)(out + gi) = t;
}

// ---------------- host ----------------

extern "C" void kernel_launch(void* const* d_in, const int* in_sizes, int n_in,
                              void* d_out, int out_size, void* d_ws, size_t ws_size,
                              hipStream_t stream) {
  const float* theta0 = (const float*)d_in[0];
  const float* ctx    = (const float*)d_in[1];
  const float* W1     = (const float*)d_in[2];
  const float* b1     = (const float*)d_in[3];
  const float* W2     = (const float*)d_in[4];
  const float* b2     = (const float*)d_in[5];
  const float* W3     = (const float*)d_in[6];
  const float* b3     = (const float*)d_in[7];
  const float* w1t    = W1 + (size_t)64 * 1024;   // time row of W1

  char* ws = (char*)d_ws;
  size_t o = 0;
  float* th    = (float*)(ws + o); o += (size_t)SN * 4;            // 2 MB
  float* acb   = (float*)(ws + o); o += (size_t)SN * 4;            // 2 MB
  float* base1 = (float*)(ws + o); o += 4096;
  u16* W2T = (u16*)(ws + o); o += (size_t)1024 * 1024 * 2;         // 2 MB
  u16* P1  = (u16*)(ws + o); o += (size_t)64 * 1024 * 2;           // 128 KB
  u16* P3  = (u16*)(ws + o); o += (size_t)1024 * 64 * 2;           // 128 KB
  float* kpart = (float*)(ws + o); o += (size_t)4 * SN * 4;        // 8 MB
  u16* h1  = (u16*)(ws + o); o += (size_t)8192 * 1024 * 2;         // 16 MB

  hipMemcpyAsync(th, theta0, (size_t)SN * 4, hipMemcpyDeviceToDevice, stream);
  hipMemsetAsync(acb, 0, (size_t)SN * 4, stream);

  k_base1<<<dim3(4), 256, 0, stream>>>(W1, b1, ctx, base1);
  k_transpose_cast<<<dim3(16, 16), 256, 0, stream>>>(W2, W2T, 1024, 1024);
  k_pack<<<dim3(32), 256, 0, stream>>>(W1, P1, 1, 1024);   // 64 ntiles x 2 ks
  k_pack<<<dim3(32), 256, 0, stream>>>(W3, P3, 5, 64);     // 4 ntiles x 32 ks

  const float hs = 1.f / NSTEPS;
  const float ah[4] = {0.f, 0.5f * hs, 0.5f * hs, hs};
  const float ct[4] = {0.f, 0.5f, 0.5f, 1.f};

  for (int step = 0; step < NSTEPS; ++step) {
    for (int s = 0; s < 4; ++s) {
      int mode = (step == 0 && s == 0) ? 0 : (s == 0 ? 2 : 1);
      float wgp = (s == 0 || s == 1) ? hs / 6.f : hs / 3.f;
      float t_s = ((float)step + ct[s]) * hs;
      k_l1<<<dim3(256), 512, 0, stream>>>(theta0, th, acb, kpart, b3, base1,
                                          w1t, P1, h1, t_s, ah[s], wgp, mode);
      k_fwd<<<dim3(128, 4), 256, 0, stream>>>(h1, W2T, b2, P3, kpart);
    }
  }
  k_out<<<dim3(512), 256, 0, stream>>>(th, acb, kpart, b3, (float*)d_out, hs / 6.f);
}

// Round 10
// 538.526 us; speedup vs baseline: 1.8148x; 1.4382x over previous
//
#include <hip/hip_runtime.h>

#define NSTEPS 3
#define SN (8192 * 64)

typedef unsigned short u16;
typedef unsigned int   u32;
typedef unsigned long long u64;
typedef __bf16 bf16x8 __attribute__((ext_vector_type(8)));
typedef float  f32x4  __attribute__((ext_vector_type(4)));

typedef __attribute__((address_space(1))) void gvoid_t;
typedef __attribute__((address_space(3))) void lvoid_t;

__device__ __forceinline__ void async_copy16(const void* g, void* l) {
  __builtin_amdgcn_global_load_lds((gvoid_t*)g, (lvoid_t*)l, 16, 0, 0);
}
__device__ __forceinline__ u16 bfc(float x) {
  union { __bf16 b; u16 u; } v; v.b = (__bf16)x; return v.u;
}
__device__ __forceinline__ u64 pack4(float a, float b, float c, float d) {
  return (u64)bfc(a) | ((u64)bfc(b) << 16) | ((u64)bfc(c) << 32) | ((u64)bfc(d) << 48);
}
__device__ __forceinline__ float ftanh(float x) {
  float e = __expf(2.f * x);
  return 1.f - 2.f / (e + 1.f);
}

// ---------------- prep kernels ----------------

// base1[j] = b1[j] + sum_c ctx[c] * W1[(65+c)*1024 + j]
__global__ __launch_bounds__(256) void k_base1(
    const float* __restrict__ W1, const float* __restrict__ b1,
    const float* __restrict__ ctx, float* __restrict__ base1) {
  int j = blockIdx.x * 256 + threadIdx.x;
  float s = b1[j];
  for (int c = 0; c < 256; ++c)
    s += ctx[c] * W1[(size_t)(65 + c) * 1024 + j];
  base1[j] = s;
}

// Pack W[K][N] f32 -> fragment-linear bf16: fid = nt*KS + ks, lane holds
// W[ks*32+(lane>>4)*8+j][nt*16+(lane&15)], j=0..7.  frag = 1024B.
__global__ __launch_bounds__(256) void k_pack(
    const float* __restrict__ W, u16* __restrict__ P, int ksl, int N) {
  int gid = blockIdx.x * 256 + threadIdx.x;
  int lane = gid & 63, fid = gid >> 6;
  int ks = fid & ((1 << ksl) - 1);
  int nt = fid >> ksl;
  int n  = nt * 16 + (lane & 15);
  int k0 = ks * 32 + (lane >> 4) * 8;
  u64 lo = pack4(W[(size_t)k0 * N + n], W[(size_t)(k0 + 1) * N + n],
                 W[(size_t)(k0 + 2) * N + n], W[(size_t)(k0 + 3) * N + n]);
  u64 hi = pack4(W[(size_t)(k0 + 4) * N + n], W[(size_t)(k0 + 5) * N + n],
                 W[(size_t)(k0 + 6) * N + n], W[(size_t)(k0 + 7) * N + n]);
  u64* dst = (u64*)(P + (size_t)gid * 8);
  dst[0] = lo; dst[1] = hi;
}

// ---------------- k_l1: RK-update + layer1 (h1 computed ONCE) ----------------
__global__ __launch_bounds__(512, 4) void k_l1(
    const float* __restrict__ theta0, float* __restrict__ th,
    float* __restrict__ acb, const float* __restrict__ kpart,
    const float* __restrict__ b3, const float* __restrict__ base1,
    const float* __restrict__ w1t, const u16* __restrict__ P1,
    u16* __restrict__ h1, float t_s, float a_h, float wgp, int mode) {
  __shared__ u16 xs[32 * 64];          // 4 KB, 128B rows, slot ^= row&7
  __shared__ float bias[1024];         // 4 KB
  __shared__ u16 bounce[8][32 * 16];   // 8 KB, 1 KB per wave
  const int tid = threadIdx.x, wid = tid >> 6, lane = tid & 63;
  const int lrow = lane & 15, lk4 = lane >> 4;
  const int brow = blockIdx.x * 32;

  bias[tid]       = base1[tid]       + t_s * w1t[tid];
  bias[tid + 512] = base1[tid + 512] + t_s * w1t[tid + 512];

  {
    int row = tid >> 4, d = (tid & 15) * 4;
    int gi = (brow + row) * 64 + d;
    f32x4 x;
    if (mode == 0) {
      x = *(const f32x4*)(theta0 + gi);
    } else {
      f32x4 kv = *(const f32x4*)(kpart + gi);
      f32x4 k1 = *(const f32x4*)(kpart + SN + gi);
      f32x4 k2 = *(const f32x4*)(kpart + 2 * SN + gi);
      f32x4 k3 = *(const f32x4*)(kpart + 3 * SN + gi);
      f32x4 bv = *(const f32x4*)(b3 + d);
      f32x4 t  = *(f32x4*)(th + gi);
      f32x4 a  = *(f32x4*)(acb + gi);
#pragma unroll
      for (int j = 0; j < 4; ++j) kv[j] += k1[j] + k2[j] + k3[j] + bv[j];
      if (mode == 1) {
#pragma unroll
        for (int j = 0; j < 4; ++j) { a[j] += wgp * kv[j]; x[j] = t[j] + a_h * kv[j]; }
        *(f32x4*)(acb + gi) = a;
      } else {
#pragma unroll
        for (int j = 0; j < 4; ++j) t[j] += a[j] + wgp * kv[j];
        *(f32x4*)(th + gi) = t;
        f32x4 z = {0.f, 0.f, 0.f, 0.f};
        *(f32x4*)(acb + gi) = z;
        x = t;
      }
    }
    int slot = d >> 3, half = (d >> 2) & 1;
    *(u64*)((char*)xs + row * 128 + ((slot ^ (row & 7)) << 4) + half * 8)
        = pack4(x[0], x[1], x[2], x[3]);
  }
  __syncthreads();

  u16* bnc = &bounce[wid][0];
#pragma unroll 1
  for (int nt = 0; nt < 8; ++nt) {
    const int n0 = wid * 128 + nt * 16;
    f32x4 acc[2] = {{0.f,0.f,0.f,0.f},{0.f,0.f,0.f,0.f}};
#pragma unroll
    for (int ks = 0; ks < 2; ++ks) {
      bf16x8 pw = *(const bf16x8*)(P1 + ((size_t)((n0 >> 4) * 2 + ks) << 9) + lane * 8);
#pragma unroll
      for (int st = 0; st < 2; ++st) {
        int row = st * 16 + lrow;
        bf16x8 xa = *(const bf16x8*)((char*)xs + row * 128 +
                                     (((ks * 4 + lk4) ^ (row & 7)) << 4));
        acc[st] = __builtin_amdgcn_mfma_f32_16x16x32_bf16(pw, xa, acc[st], 0, 0, 0);
      }
    }
    float bb0 = bias[n0 + lk4 * 4], bb1 = bias[n0 + lk4 * 4 + 1];
    float bb2 = bias[n0 + lk4 * 4 + 2], bb3 = bias[n0 + lk4 * 4 + 3];
#pragma unroll
    for (int st = 0; st < 2; ++st) {
      u64 pk = pack4(ftanh(acc[st][0] + bb0), ftanh(acc[st][1] + bb1),
                     ftanh(acc[st][2] + bb2), ftanh(acc[st][3] + bb3));
      *(u64*)((char*)bnc + (st * 16 + lrow) * 32 + lk4 * 8) = pk;
    }
    asm volatile("s_waitcnt lgkmcnt(0)" ::: "memory");
    bf16x8 ld = *(const bf16x8*)((char*)bnc + lane * 16);
    *(bf16x8*)(h1 + (size_t)(brow + (lane >> 1)) * 1024 + n0 + (lane & 1) * 8) = ld;
  }
}

// ---------------- k_fwd: layer2 + tanh + layer3-partial ----------------
// Block 64 samples x 256 h2 cols (grid 128 x 4), 256 thr = 4 waves.
// A (h1): LDS dbuf via global_load_lds (pair-packed swizzle), 2-deep.
// B (W2): DIRECT-TO-REGISTER from fragment-linear P2 (L2-hot), ping-pong
// Bf[2][4], 1-iter prefetch — no LDS round-trip, no barrier coupling.
// Issue order per iter: loadB first, stageA second (B older in vmcnt FIFO,
// so the compiler's B-reg wait never drains the newer A prefetch).
__global__ __launch_bounds__(256, 3) void k_fwd(
    const u16* __restrict__ h1, const u16* __restrict__ P2,
    const float* __restrict__ b2, const u16* __restrict__ P3,
    float* __restrict__ kpart) {
  __shared__ u16 Ab[2][64 * 32];     // 2 x 4 KB, pair-packed 128B lines
  __shared__ u16 h2L[64 * 256];      // 32 KB
  __shared__ float b2l[256];         // 1 KB
  const int tid = threadIdx.x, wid = tid >> 6, lane = tid & 63;
  const int lrow = lane & 15, lk4 = lane >> 4;
  const int brow = blockIdx.x * 64, bcol = blockIdx.y * 256;
  const int wn = wid;                 // wave col-block (4 x 64 cols)

  b2l[tid] = b2[bcol + tid];

  // pair-packed dest: slot sid -> line pr=sid>>3, s8=sid&7; logical
  // (row,kq): s8u = s8 ^ (pr&7), row = pr*2+(s8u>>2), kq = s8u&3.
  auto stageA = [&](int buf, int k0) {
    int pr = tid >> 3, s8u = (tid & 7) ^ (pr & 7);
    int row = pr * 2 + (s8u >> 2), kq = s8u & 3;
    async_copy16((const char*)h1 + ((size_t)(brow + row) * 1024 + k0 + kq * 8) * 2,
                 (char*)&Ab[buf][0] + tid * 16);
  };

  bf16x8 Bf[2][4];
  auto loadB = [&](int pb, int ks) {
#pragma unroll
    for (int n = 0; n < 4; ++n)
      Bf[pb][n] = *(const bf16x8*)(P2 +
          ((size_t)(((bcol >> 4) + wn * 4 + n) * 32 + ks) << 9) + lane * 8);
  };

  // prologue: A 2-deep, B 1-deep
  stageA(0, 0); stageA(1, 32);
  loadB(0, 0);

  f32x4 acc[4][4] = {};
  int cur = 0;
#pragma unroll 2
  for (int t = 0; t < 32; ++t) {
    // retire everything older than {A(t+1), B(t)} -> A(t) landed
    asm volatile("s_waitcnt vmcnt(5)" ::: "memory");
    __builtin_amdgcn_s_barrier();

    bf16x8 af[4];
#pragma unroll
    for (int m = 0; m < 4; ++m) {
      int ar = m * 16 + lrow;
      int pr = ar >> 1;
      af[m] = *(const bf16x8*)((const char*)&Ab[cur][0] + pr * 128 +
                               ((((ar & 1) * 4 + lk4) ^ (pr & 7)) << 4));
    }
    asm volatile("s_waitcnt lgkmcnt(0)" ::: "memory");
    __builtin_amdgcn_s_barrier();      // all waves done reading Ab[cur]

    if (t < 31) loadB((t + 1) & 1, t + 1);   // B first (older in FIFO)
    if (t < 30) stageA(cur, (t + 2) * 32);   // then A

#pragma unroll
    for (int n = 0; n < 4; ++n)
#pragma unroll
      for (int m = 0; m < 4; ++m)
        acc[n][m] = __builtin_amdgcn_mfma_f32_16x16x32_bf16(Bf[t & 1][n], af[m],
                                                            acc[n][m], 0, 0, 0);
    cur ^= 1;
  }

  // h2 tile: tanh -> h2L[64][256] (512B rows), swizzled 16B slots
#pragma unroll
  for (int n = 0; n < 4; ++n) {
    int cb = wn * 64 + n * 16 + lk4 * 4;     // 4 consecutive cols
    float c0 = b2l[cb], c1 = b2l[cb + 1], c2 = b2l[cb + 2], c3 = b2l[cb + 3];
    int o = cb >> 3, half = (cb >> 2) & 1;
#pragma unroll
    for (int m = 0; m < 4; ++m) {
      int smp = m * 16 + lrow;
      u64 pk = pack4(ftanh(acc[n][m][0] + c0), ftanh(acc[n][m][1] + c1),
                     ftanh(acc[n][m][2] + c2), ftanh(acc[n][m][3] + c3));
      int sl = (o & 24) | ((o & 7) ^ (smp & 7));
      *(u64*)((char*)h2L + smp * 512 + (sl << 4) + half * 8) = pk;
    }
  }
  __syncthreads();

  // L3 partial: D[kcol][sample], each wave 16 samples x 64 kcols, K=256
  {
    const int smp = wid * 16 + lrow;
    const char* Ar = (const char*)h2L + smp * 512;
    const int sx = smp & 7;
    f32x4 a3[4] = {};
#pragma unroll
    for (int ks = 0; ks < 8; ++ks) {
      int slu = ks * 4 + lk4;
      bf16x8 hf = *(const bf16x8*)(Ar + (((slu & 24) | ((slu & 7) ^ sx)) << 4));
#pragma unroll
      for (int n = 0; n < 4; ++n) {
        int fid = n * 32 + blockIdx.y * 8 + ks;
        bf16x8 pw = *(const bf16x8*)(P3 + ((size_t)fid << 9) + lane * 8);
        a3[n] = __builtin_amdgcn_mfma_f32_16x16x32_bf16(pw, hf, a3[n], 0, 0, 0);
      }
    }
    float* kp = kpart + (size_t)blockIdx.y * SN;
#pragma unroll
    for (int n = 0; n < 4; ++n)
      *(f32x4*)(kp + (size_t)(brow + smp) * 64 + n * 16 + lk4 * 4) = a3[n];
  }
}

// ---------------- final output ----------------
__global__ __launch_bounds__(256) void k_out(
    const float* __restrict__ th, const float* __restrict__ acb,
    const float* __restrict__ kpart, const float* __restrict__ b3,
    float* __restrict__ out, float w) {
  int gi = (blockIdx.x * 256 + threadIdx.x) * 4;
  f32x4 kv = *(const f32x4*)(kpart + gi);
  f32x4 k1 = *(const f32x4*)(kpart + SN + gi);
  f32x4 k2 = *(const f32x4*)(kpart + 2 * SN + gi);
  f32x4 k3 = *(const f32x4*)(kpart + 3 * SN + gi);
  f32x4 bv = *(const f32x4*)(b3 + (gi & 63));
  f32x4 t  = *(const f32x4*)(th + gi);
  f32x4 a  = *(const f32x4*)(acb + gi);
#pragma unroll
  for (int j = 0; j < 4; ++j)
    t[j] += a[j] + w * (kv[j] + k1[j] + k2[j] + k3[j] + bv[j]);
  *(f32x4*)(out + gi) = t;
}

// ---------------- host ----------------

extern "C" void kernel_launch(void* const* d_in, const int* in_sizes, int n_in,
                              void* d_out, int out_size, void* d_ws, size_t ws_size,
                              hipStream_t stream) {
  const float* theta0 = (const float*)d_in[0];
  const float* ctx    = (const float*)d_in[1];
  const float* W1     = (const float*)d_in[2];
  const float* b1     = (const float*)d_in[3];
  const float* W2     = (const float*)d_in[4];
  const float* b2     = (const float*)d_in[5];
  const float* W3     = (const float*)d_in[6];
  const float* b3     = (const float*)d_in[7];
  const float* w1t    = W1 + (size_t)64 * 1024;   // time row of W1

  char* ws = (char*)d_ws;
  size_t o = 0;
  float* th    = (float*)(ws + o); o += (size_t)SN * 4;            // 2 MB
  float* acb   = (float*)(ws + o); o += (size_t)SN * 4;            // 2 MB
  float* base1 = (float*)(ws + o); o += 4096;
  u16* P2  = (u16*)(ws + o); o += (size_t)1024 * 1024 * 2;         // 2 MB
  u16* P1  = (u16*)(ws + o); o += (size_t)64 * 1024 * 2;           // 128 KB
  u16* P3  = (u16*)(ws + o); o += (size_t)1024 * 64 * 2;           // 128 KB
  float* kpart = (float*)(ws + o); o += (size_t)4 * SN * 4;        // 8 MB
  u16* h1  = (u16*)(ws + o); o += (size_t)8192 * 1024 * 2;         // 16 MB

  hipMemcpyAsync(th, theta0, (size_t)SN * 4, hipMemcpyDeviceToDevice, stream);
  hipMemsetAsync(acb, 0, (size_t)SN * 4, stream);

  k_base1<<<dim3(4), 256, 0, stream>>>(W1, b1, ctx, base1);
  k_pack<<<dim3(512), 256, 0, stream>>>(W2, P2, 5, 1024);  // 64 nt x 32 ks
  k_pack<<<dim3(32),  256, 0, stream>>>(W1, P1, 1, 1024);  // 64 nt x 2 ks
  k_pack<<<dim3(32),  256, 0, stream>>>(W3, P3, 5, 64);    // 4 nt x 32 ks

  const float hs = 1.f / NSTEPS;
  const float ah[4] = {0.f, 0.5f * hs, 0.5f * hs, hs};
  const float ct[4] = {0.f, 0.5f, 0.5f, 1.f};

  for (int step = 0; step < NSTEPS; ++step) {
    for (int s = 0; s < 4; ++s) {
      int mode = (step == 0 && s == 0) ? 0 : (s == 0 ? 2 : 1);
      float wgp = (s == 0 || s == 1) ? hs / 6.f : hs / 3.f;
      float t_s = ((float)step + ct[s]) * hs;
      k_l1<<<dim3(256), 512, 0, stream>>>(theta0, th, acb, kpart, b3, base1,
                                          w1t, P1, h1, t_s, ah[s], wgp, mode);
      k_fwd<<<dim3(128, 4), 256, 0, stream>>>(h1, P2, b2, P3, kpart);
    }
  }
  k_out<<<dim3(512), 256, 0, stream>>>(th, acb, kpart, b3, (float*)d_out, hs / 6.f);
}